// Round 8
// baseline (249.787 us; speedup 1.0000x reference)
//
#include <hip/hip_runtime.h>
#include <math.h>

typedef __attribute__((ext_vector_type(8))) short short8;
typedef __attribute__((ext_vector_type(4))) float f32x4;
typedef __attribute__((ext_vector_type(4))) unsigned short ushort4_t;

#define MFMA16(a, b, c) __builtin_amdgcn_mfma_f32_16x16x32_bf16((a), (b), (c), 0, 0, 0)

// coalesced global->LDS DMA, 16B per lane; LDS dest is wave-uniform base + lane*16
#define GLOAD_LDS16(src, ldsbase)                                                     \
  __builtin_amdgcn_global_load_lds(                                                   \
      (const __attribute__((address_space(1))) void*)(src),                           \
      (__attribute__((address_space(3))) void*)(ldsbase), 16, 0, 0)

static __device__ __forceinline__ unsigned short f2bf(float f) {
  union { float f; unsigned u; } v; v.f = f;
  unsigned r = v.u + 0x7FFFu + ((v.u >> 16) & 1u);
  return (unsigned short)(r >> 16);
}

static __device__ __forceinline__ float bf2f(unsigned short b) {
  union { unsigned u; float f; } v; v.u = ((unsigned)b) << 16;
  return v.f;
}

static __device__ __forceinline__ short8 cvt2v(f32x4 a, f32x4 b) {
  short8 t;
#pragma unroll
  for (int j = 0; j < 4; ++j) t[j] = (short)f2bf(a[j]);
#pragma unroll
  for (int j = 0; j < 4; ++j) t[4 + j] = (short)f2bf(b[j]);
  return t;
}

// Barrier that waits only LDS (lgkmcnt), NOT vmcnt: lets nontemporal global
// stores stay in flight across tiles. Only legal when no barrier-carried
// dependency goes through global memory and no global_load_lds is pending.
static __device__ __forceinline__ void lds_barrier() {
  __builtin_amdgcn_sched_barrier(0);
  asm volatile("s_waitcnt lgkmcnt(0)" ::: "memory");
  __builtin_amdgcn_s_barrier();
  __builtin_amdgcn_sched_barrier(0);
}

// Merged QKV projection: z = 0/1/2 -> (q,wq)->qh, (k,wk)->kh, (v,wv)->vt.
// A fp32 reg-staged->bf16 LDS; W fp32 reg-staged->bf16 LDS (no pre-convert).
// Epilogue: z<2 frag-major qh/kh layout; z==2 frag-major vt layout.
__global__ __launch_bounds__(256) void proj_gemm(
    const float* __restrict__ q, const float* __restrict__ k, const float* __restrict__ v,
    const float* __restrict__ wq, const float* __restrict__ wk, const float* __restrict__ wv,
    const float* __restrict__ bq, const float* __restrict__ bk, const float* __restrict__ bv,
    unsigned short* __restrict__ qh, unsigned short* __restrict__ kh,
    unsigned short* __restrict__ vt) {
  __shared__ unsigned short As[128 * 64], Ws[128 * 64];
  const int z = blockIdx.z;
  const float* A = z == 0 ? q : z == 1 ? k : v;
  const float* W = z == 0 ? wq : z == 1 ? wk : wv;
  const float* bias = z == 0 ? bq : z == 1 ? bk : bv;
  unsigned short* outp = z == 0 ? qh : z == 1 ? kh : vt;

  const int tid = threadIdx.x;
  const int wv_ = tid >> 6, lane = tid & 63;
  const int lr = lane & 15, lg = lane >> 4;
  const int m0 = blockIdx.x * 128, n0 = blockIdx.y * 128;
  const int wm = (wv_ >> 1) * 64, wn = (wv_ & 1) * 64;

  f32x4 acc[4][4] = {};

  for (int k0 = 0; k0 < 512; k0 += 64) {
    const int row = (tid >> 3), col = (tid & 7) * 8;
#pragma unroll
    for (int p = 0; p < 4; ++p) {
      const float* src = A + (size_t)(m0 + p * 32 + row) * 512 + k0 + col;
      f32x4 a0 = *(const f32x4*)src;
      f32x4 a1 = *(const f32x4*)(src + 4);
      *(short8*)&As[(p * 32 + row) * 64 + col] = cvt2v(a0, a1);
    }
#pragma unroll
    for (int p = 0; p < 4; ++p) {
      const float* src = W + (size_t)(n0 + p * 32 + row) * 512 + k0 + col;
      f32x4 a0 = *(const f32x4*)src;
      f32x4 a1 = *(const f32x4*)(src + 4);
      *(short8*)&Ws[(p * 32 + row) * 64 + col] = cvt2v(a0, a1);
    }
    __syncthreads();

#pragma unroll
    for (int ks = 0; ks < 2; ++ks) {
      short8 af[4], bw[4];
#pragma unroll
      for (int mi = 0; mi < 4; ++mi)
        af[mi] = *(const short8*)&As[(wm + mi * 16 + lr) * 64 + ks * 32 + lg * 8];
#pragma unroll
      for (int ni = 0; ni < 4; ++ni)
        bw[ni] = *(const short8*)&Ws[(wn + ni * 16 + lr) * 64 + ks * 32 + lg * 8];
#pragma unroll
      for (int mi = 0; mi < 4; ++mi)
#pragma unroll
        for (int ni = 0; ni < 4; ++ni)
          acc[mi][ni] = MFMA16(af[mi], bw[ni], acc[mi][ni]);
    }
    __syncthreads();
  }

#pragma unroll
  for (int ni = 0; ni < 4; ++ni) {
    const int c = n0 + wn + ni * 16 + lr;
    const float bv_ = bias[c];
#pragma unroll
    for (int mi = 0; mi < 4; ++mi) {
#pragma unroll
      for (int r = 0; r < 4; ++r) {
        const int rg = m0 + wm + mi * 16 + 4 * lg + r;
        const float val = acc[mi][ni][r] + bv_;
        const int bI = rg >> 10, s = rg & 1023, hI = c >> 6, d = c & 63;
        size_t addr;
        if (z < 2)
          // fragment-major qh/kh: [sblk][ks][lg][lr=s&15][j=d&7]
          addr = ((size_t)(bI * 8 + hI) << 16) + (s >> 4) * 1024 + (d >> 5) * 512 +
                 ((d >> 3) & 3) * 128 + (s & 15) * 8 + (d & 7);
        else
          // fragment-major vt: [kt][ni][ks][lg][lr=d&15][j=s&7]
          addr = ((size_t)(bI * 8 + hI) << 16) + (s >> 6) * 4096 + (d >> 4) * 1024 +
                 ((s >> 5) & 1) * 512 + ((s >> 3) & 3) * 128 + (d & 15) * 8 + (s & 7);
        outp[addr] = f2bf(val);
      }
    }
  }
}

// Final out-projection: A = ctx bf16 (global_load_lds), W = wo fp32 reg-converted.
__global__ __launch_bounds__(256) void out_gemm(const unsigned short* __restrict__ A,
                                                const float* __restrict__ W,
                                                const float* __restrict__ bias,
                                                float* __restrict__ out_) {
  __shared__ unsigned short As[128 * 64], Ws[128 * 64];
  const int tid = threadIdx.x;
  const int wv_ = tid >> 6, lane = tid & 63;
  const int lr = lane & 15, lg = lane >> 4;
  const int m0 = blockIdx.x * 128, n0 = blockIdx.y * 128;
  const int wm = (wv_ >> 1) * 64, wn = (wv_ & 1) * 64;

  f32x4 acc[4][4] = {};

  for (int k0 = 0; k0 < 512; k0 += 64) {
#pragma unroll
    for (int p = 0; p < 4; ++p) {
      const int row = (p * 4 + wv_) * 8 + (lane >> 3);
      const int col = (lane & 7) * 8;
      GLOAD_LDS16(A + (size_t)(m0 + row) * 512 + k0 + col, &As[(p * 4 + wv_) * 512]);
    }
    const int row = (tid >> 3), col = (tid & 7) * 8;
#pragma unroll
    for (int p = 0; p < 4; ++p) {
      const float* src = W + (size_t)(n0 + p * 32 + row) * 512 + k0 + col;
      f32x4 a0 = *(const f32x4*)src;
      f32x4 a1 = *(const f32x4*)(src + 4);
      *(short8*)&Ws[(p * 32 + row) * 64 + col] = cvt2v(a0, a1);
    }
    __syncthreads();  // drains vmcnt (gload_lds) + lgkmcnt (ds_write)

#pragma unroll
    for (int ks = 0; ks < 2; ++ks) {
      short8 af[4], bw[4];
#pragma unroll
      for (int mi = 0; mi < 4; ++mi)
        af[mi] = *(const short8*)&As[(wm + mi * 16 + lr) * 64 + ks * 32 + lg * 8];
#pragma unroll
      for (int ni = 0; ni < 4; ++ni)
        bw[ni] = *(const short8*)&Ws[(wn + ni * 16 + lr) * 64 + ks * 32 + lg * 8];
#pragma unroll
      for (int mi = 0; mi < 4; ++mi)
#pragma unroll
        for (int ni = 0; ni < 4; ++ni)
          acc[mi][ni] = MFMA16(af[mi], bw[ni], acc[mi][ni]);
    }
    __syncthreads();
  }

#pragma unroll
  for (int ni = 0; ni < 4; ++ni) {
    const int c = n0 + wn + ni * 16 + lr;
    const float bv_ = bias[c];
#pragma unroll
    for (int mi = 0; mi < 4; ++mi)
#pragma unroll
      for (int r = 0; r < 4; ++r) {
        const int rg = m0 + wm + mi * 16 + 4 * lg + r;
        out_[(size_t)rg * 512 + c] = acc[mi][ni][r] + bv_;
      }
  }
}

// Fused attention v6: fragment-major Q/K/V, mask precomputed in LDS,
// split V prefetch (ks0 before B1, ks1 before B2), double-buffered bf16 LDS,
// lgkm-only barriers, swapped QK^T, in-place prob write-back, XCD swizzle.
__global__ __launch_bounds__(512, 4) void attn_fused(
    const unsigned short* __restrict__ qh, const unsigned short* __restrict__ kh,
    const unsigned short* __restrict__ vt, const int* __restrict__ mask,
    float* __restrict__ attn_out, unsigned short* __restrict__ ctx) {
  __shared__ unsigned short sb[2][8][32][72];  // bf16 logits->probs, dbuf
  __shared__ float mf[1024];                   // -1e9 * mask[b][k]

  const int tid = threadIdx.x;
  const int h = tid >> 6, lane = tid & 63;
  const int lr = lane & 15, lg = lane >> 4;

  const int lin = blockIdx.x + 32 * blockIdx.y;
  const int xcd = lin & 7, slot = lin >> 3;
  const int b = xcd + 8 * (slot >> 5);
  const int q0 = (slot & 31) * 32;

  const unsigned short* qb = qh + ((size_t)(b * 8 + h) << 16);
  const unsigned short* kb = kh + ((size_t)(b * 8 + h) << 16);
  const unsigned short* vb = vt + ((size_t)(b * 8 + h) << 16);
  const int* mrow = mask + b * 1024;

  // mask -> LDS once
#pragma unroll
  for (int i = 0; i < 2; ++i) mf[tid + i * 512] = -1e9f * (float)mrow[tid + i * 512];

  short8 qf[2][2];
#pragma unroll
  for (int qi = 0; qi < 2; ++qi)
#pragma unroll
    for (int ks = 0; ks < 2; ++ks)
      qf[qi][ks] = *(const short8*)(qb + ((q0 >> 4) + qi) * 1024 + ks * 512 + lane * 8);

  const int sq = tid >> 4, sk4 = tid & 15;

  f32x4 apv[2][4] = {};

  lds_barrier();  // mf visible

  for (int kt = 0; kt < 16; ++kt) {
    const int k0 = kt * 64;
    unsigned short(*sc)[32][72] = sb[kt & 1];

    // ---- swapped QK^T; K fragments coalesced
    short8 kf[4][2];
#pragma unroll
    for (int ki = 0; ki < 4; ++ki)
#pragma unroll
      for (int ks = 0; ks < 2; ++ks)
        kf[ki][ks] = *(const short8*)(kb + ((k0 >> 4) + ki) * 1024 + ks * 512 + lane * 8);
    f32x4 aqk[4][2] = {};
#pragma unroll
    for (int ks = 0; ks < 2; ++ks)
#pragma unroll
      for (int ki = 0; ki < 4; ++ki)
#pragma unroll
        for (int qi = 0; qi < 2; ++qi)
          aqk[ki][qi] = MFMA16(kf[ki][ks], qf[qi][ks], aqk[ki][qi]);

    // ---- logit stores (bf16); mask from LDS (broadcast reads)
#pragma unroll
    for (int ki = 0; ki < 4; ++ki) {
      f32x4 mv = *(const f32x4*)&mf[k0 + ki * 16 + 4 * lg];
#pragma unroll
      for (int qi = 0; qi < 2; ++qi) {
        ushort4_t pk;
#pragma unroll
        for (int r = 0; r < 4; ++r) pk[r] = f2bf(aqk[ki][qi][r] * 0.125f + mv[r]);
        *(ushort4_t*)&sc[h][qi * 16 + lr][ki * 16 + 4 * lg] = pk;
      }
    }

    // ---- V prefetch, first half (covered by softmax)
    short8 vf0[4];
#pragma unroll
    for (int ni = 0; ni < 4; ++ni)
      vf0[ni] = *(const short8*)(vb + kt * 4096 + ni * 1024 + lane * 8);

    lds_barrier();  // B1: logits visible; nt stores keep streaming

    // ---- softmax over 8 heads; thread owns (sq, 4 k); in-place write-back
    f32x4 e[8];
#pragma unroll
    for (int hh = 0; hh < 8; ++hh) {
      ushort4_t raw = *(const ushort4_t*)&sc[hh][sq][4 * sk4];
#pragma unroll
      for (int r = 0; r < 4; ++r) e[hh][r] = bf2f(raw[r]);
    }
    f32x4 mx = e[0];
#pragma unroll
    for (int hh = 1; hh < 8; ++hh)
#pragma unroll
      for (int r = 0; r < 4; ++r) mx[r] = fmaxf(mx[r], e[hh][r]);
    f32x4 s = {0.f, 0.f, 0.f, 0.f};
#pragma unroll
    for (int hh = 0; hh < 8; ++hh) {
#pragma unroll
      for (int r = 0; r < 4; ++r) e[hh][r] = __expf(e[hh][r] - mx[r]);
      s += e[hh];
    }
    f32x4 inv;
#pragma unroll
    for (int r = 0; r < 4; ++r) inv[r] = __builtin_amdgcn_rcpf(s[r]);

    float* abase = attn_out + (((size_t)(b * 8) * 1024 + q0 + sq) * 1024) + k0 + 4 * sk4;
#pragma unroll
    for (int hh = 0; hh < 8; ++hh) {
      f32x4 p = e[hh] * inv;
      __builtin_nontemporal_store(p, (f32x4*)(abase + ((size_t)hh << 20)));
      ushort4_t pk;
#pragma unroll
      for (int r = 0; r < 4; ++r) pk[r] = f2bf(p[r]);
      *(ushort4_t*)&sc[hh][sq][4 * sk4] = pk;  // same-thread in-place rewrite
    }

    // ---- V prefetch, second half (covered by prob visibility + PV ks0)
    short8 vf1[4];
#pragma unroll
    for (int ni = 0; ni < 4; ++ni)
      vf1[ni] = *(const short8*)(vb + kt * 4096 + ni * 1024 + 512 + lane * 8);

    lds_barrier();  // B2: probs visible to PV

    // ---- PV: A = probs (LDS), B = V fragments
    short8 pf[2][2];
#pragma unroll
    for (int mi = 0; mi < 2; ++mi)
#pragma unroll
      for (int ks = 0; ks < 2; ++ks)
        pf[mi][ks] = *(const short8*)&sc[h][mi * 16 + lr][ks * 32 + 8 * lg];
#pragma unroll
    for (int mi = 0; mi < 2; ++mi)
#pragma unroll
      for (int ni = 0; ni < 4; ++ni)
        apv[mi][ni] = MFMA16(pf[mi][0], vf0[ni], apv[mi][ni]);
#pragma unroll
    for (int mi = 0; mi < 2; ++mi)
#pragma unroll
      for (int ni = 0; ni < 4; ++ni)
        apv[mi][ni] = MFMA16(pf[mi][1], vf1[ni], apv[mi][ni]);
  }

  // ---- write merged ctx [B,S,512] bf16
#pragma unroll
  for (int mi = 0; mi < 2; ++mi)
#pragma unroll
    for (int ni = 0; ni < 4; ++ni)
#pragma unroll
      for (int r = 0; r < 4; ++r) {
        const int row = q0 + mi * 16 + 4 * lg + r;
        const int col = h * 64 + ni * 16 + lr;
        ctx[((size_t)b * 1024 + row) * 512 + col] = f2bf(apv[mi][ni][r]);
      }
}

extern "C" void kernel_launch(void* const* d_in, const int* in_sizes, int n_in,
                              void* d_out, int out_size, void* d_ws, size_t ws_size,
                              hipStream_t stream) {
  const float* q = (const float*)d_in[0];
  const float* k = (const float*)d_in[1];
  const float* v = (const float*)d_in[2];
  const int* mask = (const int*)d_in[3];
  const float* wq_w = (const float*)d_in[4];
  const float* wq_b = (const float*)d_in[5];
  const float* wk_w = (const float*)d_in[6];
  const float* wk_b = (const float*)d_in[7];
  const float* wv_w = (const float*)d_in[8];
  const float* wv_b = (const float*)d_in[9];
  const float* wo_w = (const float*)d_in[10];
  const float* wo_b = (const float*)d_in[11];

  float* out = (float*)d_out;                   // [16,1024,512]
  float* attn = out + (size_t)16 * 1024 * 512;  // [16,8,1024,1024] fp32

  unsigned short* qh = (unsigned short*)d_ws;              // frag-major [B,H][...]
  unsigned short* kh = qh + (size_t)16 * 8 * 1024 * 64;
  unsigned short* vt = kh + (size_t)16 * 8 * 1024 * 64;
  unsigned short* ctx = vt + (size_t)16 * 8 * 1024 * 64;   // [16,1024,512]

  proj_gemm<<<dim3(128, 4, 3), dim3(256), 0, stream>>>(
      q, k, v, wq_w, wk_w, wv_w, wq_b, wk_b, wv_b, qh, kh, vt);
  attn_fused<<<dim3(32, 16), dim3(512), 0, stream>>>(qh, kh, vt, mask, attn, ctx);
  out_gemm<<<dim3(128, 4), dim3(256), 0, stream>>>(ctx, wo_w, wo_b, out);
}